// Round 6
// baseline (243.664 us; speedup 1.0000x reference)
//
#include <hip/hip_runtime.h>
#include <cstdint>

#define N_NODES 100000
#define E_EDGES 1600000
#define TOTAL_E (E_EDGES + N_NODES)
#define IN_F 128
#define OUT_F 64
#define NEG_SLOPE 0.2f

#define NB   256     // coarse buckets
#define RPB  391     // rows per bucket: ceil(100000/256)
#define GCAP 8192    // per-bucket record capacity
#define TILE 2048    // edges per k_bin tile
#define EPT  (TILE / 256)
#define HALF_R 196   // rows in half 0 (half 1 gets RPB-196 = 195)
#define CCAP 4608    // per-half CSR capacity (mean 3332, +22 sigma)

#define GC_PAD 16    // gcur stride: one counter per 64B cache line

#define BIN_BLOCKS ((TOTAL_E + TILE - 1) / TILE)   // 831

typedef __attribute__((ext_vector_type(8))) short short8;
typedef __attribute__((ext_vector_type(4))) float float4v;

__device__ __forceinline__ short bf16_rne(float x) {
  unsigned u = __builtin_bit_cast(unsigned, x);
  unsigned r = u + 0x7FFFu + ((u >> 16) & 1u);
  return (short)(r >> 16);
}
__device__ __forceinline__ float bf16_f(short s) {
  unsigned u = ((unsigned)(unsigned short)s) << 16;
  return __builtin_bit_cast(float, u);
}
__device__ __forceinline__ float bf16u_f(unsigned short s) {
  unsigned u = ((unsigned)s) << 16;
  return __builtin_bit_cast(float, u);
}

// ---------------------------------------------------------------------------
// Kernel A (MFMA): h_lin(bf16) = h @ W^T, fused s_src/s_dst. UNCHANGED.
// ---------------------------------------------------------------------------
__global__ __launch_bounds__(256) void k_linear(
    const float* __restrict__ h, const float* __restrict__ W,
    const float* __restrict__ a, unsigned short* __restrict__ h_lin,
    float* __restrict__ s_src, float* __restrict__ s_dst) {
  __shared__ alignas(16) short Whi[16 * 512];
  __shared__ alignas(16) short Wlo[16 * 512];

  const int tid = threadIdx.x;
  for (int i = tid; i < OUT_F * IN_F; i += 256) {
    const int n = i >> 7, k = i & 127;
    const float x = W[i];
    const short hi = bf16_rne(x);
    const short lo = bf16_rne(x - bf16_f(hi));
    const int idx = (((k >> 5) * 4 + (n >> 4)) << 9) |
                    (((((k >> 3) & 3) << 4) | (n & 15)) << 3) | (k & 7);
    Whi[idx] = hi;
    Wlo[idx] = lo;
  }
  __syncthreads();

  const int lane = tid & 63;
  const int m    = lane & 15;
  const int q    = lane >> 4;
  const int wgid = blockIdx.x * 4 + (tid >> 6);
  const int nw   = gridDim.x * 4;

  float a1v[4], a2v[4];
#pragma unroll
  for (int t = 0; t < 4; ++t) {
    a1v[t] = a[t * 16 + m];
    a2v[t] = a[OUT_F + t * 16 + m];
  }

  for (int tile = wgid; tile < N_NODES / 16; tile += nw) {
    const int row0 = tile * 16;
    float4v acc[4] = {{0.f,0.f,0.f,0.f},{0.f,0.f,0.f,0.f},
                      {0.f,0.f,0.f,0.f},{0.f,0.f,0.f,0.f}};

    const float* hbase = h + (size_t)(row0 + m) * IN_F + q * 8;
#pragma unroll
    for (int ks = 0; ks < 4; ++ks) {
      const float4 f0 = *(const float4*)(hbase + 32 * ks);
      const float4 f1 = *(const float4*)(hbase + 32 * ks + 4);
      float av[8] = {f0.x, f0.y, f0.z, f0.w, f1.x, f1.y, f1.z, f1.w};
      short8 ahi, alo;
#pragma unroll
      for (int j = 0; j < 8; ++j) {
        const short hi = bf16_rne(av[j]);
        ahi[j] = hi;
        alo[j] = bf16_rne(av[j] - bf16_f(hi));
      }
#pragma unroll
      for (int t = 0; t < 4; ++t) {
        const int fb = ((ks * 4 + t) << 9) + lane * 8;
        const short8 bhi = *(const short8*)&Whi[fb];
        const short8 blo = *(const short8*)&Wlo[fb];
        acc[t] = __builtin_amdgcn_mfma_f32_16x16x32_bf16(ahi, bhi, acc[t], 0, 0, 0);
        acc[t] = __builtin_amdgcn_mfma_f32_16x16x32_bf16(ahi, blo, acc[t], 0, 0, 0);
        acc[t] = __builtin_amdgcn_mfma_f32_16x16x32_bf16(alo, bhi, acc[t], 0, 0, 0);
      }
    }

    // store h_lin in bf16: C/D layout col=lane&15, row=q*4+r
#pragma unroll
    for (int t = 0; t < 4; ++t)
#pragma unroll
      for (int r = 0; r < 4; ++r)
        h_lin[(size_t)(row0 + q * 4 + r) * OUT_F + t * 16 + m] =
            (unsigned short)bf16_rne(acc[t][r]);

#pragma unroll
    for (int r = 0; r < 4; ++r) {
      float p = acc[0][r] * a1v[0] + acc[1][r] * a1v[1] +
                acc[2][r] * a1v[2] + acc[3][r] * a1v[3];
      float qq = acc[0][r] * a2v[0] + acc[1][r] * a2v[1] +
                 acc[2][r] * a2v[2] + acc[3][r] * a2v[3];
#pragma unroll
      for (int o = 1; o < 16; o <<= 1) {
        p  += __shfl_xor(p, o, 64);
        qq += __shfl_xor(qq, o, 64);
      }
      if (m == 0) {
        s_src[row0 + q * 4 + r] = p;
        s_dst[row0 + q * 4 + r] = qq;
      }
    }
  }
}

// ---------------------------------------------------------------------------
// Kernel B: binning. ONE CHANGE: also accumulate per-row record counts into
// global rowcnt[] (1.7M atomics spread over 100K addresses, ~17/address,
// hidden under the existing latency slack). Everything else identical.
// ---------------------------------------------------------------------------
__global__ __launch_bounds__(256) void k_bin(
    const int* __restrict__ ei, int* __restrict__ gcur,
    int* __restrict__ rowcnt, unsigned* __restrict__ regions) {
  __shared__ unsigned reord[TILE];
  __shared__ unsigned char bktid[TILE];
  __shared__ int hist[NB];
  __shared__ int scan_s[NB];
  __shared__ int adj[NB];
  __shared__ int wsum[4];

  const int tid = threadIdx.x;
  const int e0  = blockIdx.x * TILE;

  hist[tid] = 0;
  __syncthreads();

  int      myb[EPT];
  unsigned myrec[EPT];
#pragma unroll
  for (int k = 0; k < EPT; ++k) {
    const int e = e0 + k * 256 + tid;
    int b = -1; unsigned rec = 0;
    if (e < TOTAL_E) {
      int r, c;
      if (e < E_EDGES) { r = ei[e]; c = ei[E_EDGES + e]; }
      else             { r = e - E_EDGES; c = r; }
      b = (int)((unsigned)r / RPB);
      rec = ((unsigned)(r - b * RPB) << 17) | (unsigned)c;
      atomicAdd(&hist[b], 1);
      atomicAdd(&rowcnt[r], 1);          // per-row count for k_agg phase 1
    }
    myb[k] = b; myrec[k] = rec;
  }
  __syncthreads();

  // issue the global atomic early; consume its result late
  const int v = hist[tid];
  int base = 0;
  if (v > 0) base = atomicAdd(&gcur[tid * GC_PAD], v);

  const int lane = tid & 63, w = tid >> 6;
  {
    int incl = v;
#pragma unroll
    for (int o = 1; o < 64; o <<= 1) {
      const int t = __shfl_up(incl, o, 64);
      if (lane >= o) incl += t;
    }
    if (lane == 63) wsum[w] = incl;
    __syncthreads();
    int wpre = 0;
    for (int i = 0; i < w; ++i) wpre += wsum[i];
    scan_s[tid] = wpre + incl - v;
    adj[tid]    = wpre + incl - v;
  }
  __syncthreads();

#pragma unroll
  for (int k = 0; k < EPT; ++k) {
    if (myb[k] >= 0) {
      const int pos = atomicAdd(&adj[myb[k]], 1);
      reord[pos]  = myrec[k];
      bktid[pos]  = (unsigned char)myb[k];
    }
  }
  __syncthreads();

  adj[tid] = base - scan_s[tid];
  __syncthreads();

  const int tilesz = scan_s[NB - 1] + hist[NB - 1];
  for (int i = tid; i < tilesz; i += 256) {
    const int b    = bktid[i];
    const int slot = adj[b] + i;
    if (slot < GCAP) regions[(size_t)b * GCAP + slot] = reord[i];
  }
}

// ---------------------------------------------------------------------------
// Kernel C: phase 1 (full record-count pass) REPLACED by a coalesced load
// of precomputed rowcnt — removes one of three record passes, 1.7M LDS
// atomics, and its decode VALU. Phases 2-4 unchanged.
// ---------------------------------------------------------------------------
__global__ __launch_bounds__(1024) void k_agg(
    const unsigned short* __restrict__ h_lin, const float* __restrict__ s_src,
    const float* __restrict__ s_dst, const int* __restrict__ gcur,
    const int* __restrict__ rowcnt, const unsigned* __restrict__ regions,
    float* __restrict__ out) {
  __shared__ int   cnt[HALF_R];
  __shared__ int   off[HALF_R];
  __shared__ float srcs[HALF_R];
  __shared__ uint2 pairs[CCAP];      // 36 KB: (col, exp(e)) per record
  __shared__ int   wsum4[4];

  const int blk  = blockIdx.x;
  const int b    = blk >> 1;
  const int half = blk & 1;
  const int rlo  = half * HALF_R;
  const int hr   = half ? (RPB - HALF_R) : HALF_R;   // 195 : 196
  const int tid  = threadIdx.x;
  const int row0 = b * RPB + rlo;
  const int m    = min(gcur[b * GC_PAD], GCAP);
  const unsigned* reg = regions + (size_t)b * GCAP;

  // phase 1: per-row counts precomputed by k_bin (coalesced 196-int load)
  for (int i = tid; i < HALF_R; i += 1024) {
    const int row = row0 + i;
    const bool ok = (i < hr) && (row < N_NODES);
    cnt[i]  = ok ? rowcnt[row] : 0;
    srcs[i] = ok ? s_src[row] : 0.f;
  }
  __syncthreads();

  // phase 2: exclusive scan of cnt[0..hr) using first 4 waves
  const int lane = tid & 63, wv = tid >> 6;
  int incl = 0, v = 0;
  if (tid < 256) {
    v = (tid < hr) ? cnt[tid] : 0;
    incl = v;
#pragma unroll
    for (int o = 1; o < 64; o <<= 1) {
      const int t = __shfl_up(incl, o, 64);
      if (lane >= o) incl += t;
    }
    if (lane == 63) wsum4[wv] = incl;
  }
  __syncthreads();
  if (tid < hr) {
    int wpre = 0;
    for (int i = 0; i < wv; ++i) wpre += wsum4[i];
    off[tid] = wpre + incl - v;
  }
  __syncthreads();

  // phase 3: read records (L2-hot), compute ex inline with full lane
  // utilization, scatter (col, ex) into the LDS CSR
  for (int i = tid; i < m; i += 1024) {
    const unsigned rec = reg[i];
    const int rl = (int)(rec >> 17) - rlo;
    if (rl >= 0 && rl < hr) {
      const int c = (int)(rec & 0x1FFFFu);
      float e = srcs[rl] + s_dst[c];
      e = e > 0.f ? e : NEG_SLOPE * e;
      const float ex = __expf(e);
      const int pos = atomicAdd(&off[rl], 1);
      if (pos < CCAP) pairs[pos] = make_uint2((unsigned)c, __float_as_uint(ex));
    }
  }
  __syncthreads();

  // phase 4: per-row weighted sum. One wave per row. Quarter-wave (16 lanes)
  // per edge; each lane owns 4 features. 8 edges per iteration, both load
  // groups issued before any use (2-deep MLP).
  const int qid = lane >> 4;           // quarter id: which edge in group of 4
  const int f4  = (lane & 15) * 4;     // feature base (4 features per lane)
  for (int rl = wv; rl < hr; rl += 16) {
    const int row = row0 + rl;
    if (row >= N_NODES) break;
    const int dcnt  = cnt[rl];
    const int end   = off[rl];
    const int start = end - dcnt;
    const uint2* prow = pairs + start;

    float4v acc = {0.f, 0.f, 0.f, 0.f};
    float dsum = 0.f;
    for (int j = 0; j < dcnt; j += 8) {
      const int ja = j + qid;
      const int jb = j + 4 + qid;
      uint2 pa = make_uint2(0u, 0u), pb = make_uint2(0u, 0u);
      if (ja < dcnt) pa = prow[ja];
      if (jb < dcnt) pb = prow[jb];
      // both gathers issued back-to-back (independent)
      const ushort4 ha = *(const ushort4*)&h_lin[(size_t)pa.x * OUT_F + f4];
      const ushort4 hb = *(const ushort4*)&h_lin[(size_t)pb.x * OUT_F + f4];
      const float ea = __uint_as_float(pa.y);
      const float eb = __uint_as_float(pb.y);
      acc.x = fmaf(ea, bf16u_f(ha.x), acc.x);
      acc.y = fmaf(ea, bf16u_f(ha.y), acc.y);
      acc.z = fmaf(ea, bf16u_f(ha.z), acc.z);
      acc.w = fmaf(ea, bf16u_f(ha.w), acc.w);
      acc.x = fmaf(eb, bf16u_f(hb.x), acc.x);
      acc.y = fmaf(eb, bf16u_f(hb.y), acc.y);
      acc.z = fmaf(eb, bf16u_f(hb.z), acc.z);
      acc.w = fmaf(eb, bf16u_f(hb.w), acc.w);
      dsum += ea + eb;
    }

    // reduce over the 4 quarter-waves (lanes l, l+16, l+32, l+48 share f4)
    acc.x += __shfl_xor(acc.x, 16, 64);
    acc.y += __shfl_xor(acc.y, 16, 64);
    acc.z += __shfl_xor(acc.z, 16, 64);
    acc.w += __shfl_xor(acc.w, 16, 64);
    dsum  += __shfl_xor(dsum, 16, 64);
    acc.x += __shfl_xor(acc.x, 32, 64);
    acc.y += __shfl_xor(acc.y, 32, 64);
    acc.z += __shfl_xor(acc.z, 32, 64);
    acc.w += __shfl_xor(acc.w, 32, 64);
    dsum  += __shfl_xor(dsum, 32, 64);

    if (lane < 16) {
      const float inv = 1.f / dsum;
      float4 o;
      o.x = acc.x * inv; o.y = acc.y * inv;
      o.z = acc.z * inv; o.w = acc.w * inv;
      o.x = o.x > 0.f ? o.x : __expf(o.x) - 1.f;
      o.y = o.y > 0.f ? o.y : __expf(o.y) - 1.f;
      o.z = o.z > 0.f ? o.z : __expf(o.z) - 1.f;
      o.w = o.w > 0.f ? o.w : __expf(o.w) - 1.f;
      *(float4*)&out[(size_t)row * OUT_F + f4] = o;
    }
  }
}

// ---------------------------------------------------------------------------
extern "C" void kernel_launch(void* const* d_in, const int* in_sizes, int n_in,
                              void* d_out, int out_size, void* d_ws, size_t ws_size,
                              hipStream_t stream) {
  const float* h  = (const float*)d_in[0];
  const float* W  = (const float*)d_in[1];
  const float* a  = (const float*)d_in[2];
  const int*   ei = (const int*)d_in[3];
  float* out = (float*)d_out;

  unsigned short* h_lin = (unsigned short*)d_ws;                 // N*64 bf16
  float* s_src = (float*)(h_lin + (size_t)N_NODES * OUT_F);      // N
  float* s_dst = s_src + N_NODES;                                // N
  int*   gcur  = (int*)(s_dst + N_NODES);                        // NB*GC_PAD
  int*   rowcnt = gcur + NB * GC_PAD;                            // N ints
  unsigned* regions = (unsigned*)(rowcnt + N_NODES);             // NB*GCAP u32

  // one memset covers gcur + rowcnt (contiguous)
  hipMemsetAsync(gcur, 0, (NB * GC_PAD + N_NODES) * sizeof(int), stream);

  k_linear<<<782, 256, 0, stream>>>(h, W, a, h_lin, s_src, s_dst);

  k_bin<<<BIN_BLOCKS, 256, 0, stream>>>(ei, gcur, rowcnt, regions);

  // 2 blocks per bucket -> 512 blocks = 2/CU = full 32 waves/CU
  k_agg<<<NB * 2, 1024, 0, stream>>>(h_lin, s_src, s_dst, gcur, rowcnt,
                                     regions, out);
}

// Round 7
// 195.213 us; speedup vs baseline: 1.2482x; 1.2482x over previous
//
#include <hip/hip_runtime.h>
#include <cstdint>

#define N_NODES 100000
#define E_EDGES 1600000
#define TOTAL_E (E_EDGES + N_NODES)
#define IN_F 128
#define OUT_F 64
#define NEG_SLOPE 0.2f

#define NB_F 512     // fine buckets: 1 k_agg block per bucket (no half-split)
#define RPB  196     // rows per bucket: ceil(100000/512)
#define GCAP 4608    // per-bucket record capacity (mean 3332, +22 sigma)
#define CCAP 4608    // per-block CSR capacity (== GCAP, all records belong)
#define TILE 2048    // edges per bin tile
#define EPT  (TILE / 256)

#define GC_PAD 16    // gcur stride: one counter per 64B cache line

#define BIN_BLOCKS ((TOTAL_E + TILE - 1) / TILE)   // 831
#define GEMM_BLOCKS 608
#define FRONT_BLOCKS (BIN_BLOCKS + GEMM_BLOCKS)    // 1439

typedef __attribute__((ext_vector_type(8))) short short8;
typedef __attribute__((ext_vector_type(4))) float float4v;

__device__ __forceinline__ short bf16_rne(float x) {
  unsigned u = __builtin_bit_cast(unsigned, x);
  unsigned r = u + 0x7FFFu + ((u >> 16) & 1u);
  return (short)(r >> 16);
}
__device__ __forceinline__ float bf16_f(short s) {
  unsigned u = ((unsigned)(unsigned short)s) << 16;
  return __builtin_bit_cast(float, u);
}
__device__ __forceinline__ float bf16u_f(unsigned short s) {
  unsigned u = ((unsigned)s) << 16;
  return __builtin_bit_cast(float, u);
}

// ---------------------------------------------------------------------------
// GEMM body (identical math to previous rounds; smem carved from arena)
// ---------------------------------------------------------------------------
__device__ __forceinline__ void gemm_body(
    char* smem, int gbid,
    const float* __restrict__ h, const float* __restrict__ W,
    const float* __restrict__ a, unsigned short* __restrict__ h_lin,
    float* __restrict__ s_src, float* __restrict__ s_dst) {
  short* Whi = (short*)smem;              // 16 KB
  short* Wlo = (short*)(smem + 16384);    // 16 KB

  const int tid = threadIdx.x;
  for (int i = tid; i < OUT_F * IN_F; i += 256) {
    const int n = i >> 7, k = i & 127;
    const float x = W[i];
    const short hi = bf16_rne(x);
    const short lo = bf16_rne(x - bf16_f(hi));
    const int idx = (((k >> 5) * 4 + (n >> 4)) << 9) |
                    (((((k >> 3) & 3) << 4) | (n & 15)) << 3) | (k & 7);
    Whi[idx] = hi;
    Wlo[idx] = lo;
  }
  __syncthreads();

  const int lane = tid & 63;
  const int m    = lane & 15;
  const int q    = lane >> 4;
  const int wgid = gbid * 4 + (tid >> 6);
  const int nw   = GEMM_BLOCKS * 4;

  float a1v[4], a2v[4];
#pragma unroll
  for (int t = 0; t < 4; ++t) {
    a1v[t] = a[t * 16 + m];
    a2v[t] = a[OUT_F + t * 16 + m];
  }

  for (int tile = wgid; tile < N_NODES / 16; tile += nw) {
    const int row0 = tile * 16;
    float4v acc[4] = {{0.f,0.f,0.f,0.f},{0.f,0.f,0.f,0.f},
                      {0.f,0.f,0.f,0.f},{0.f,0.f,0.f,0.f}};

    const float* hbase = h + (size_t)(row0 + m) * IN_F + q * 8;
#pragma unroll
    for (int ks = 0; ks < 4; ++ks) {
      const float4 f0 = *(const float4*)(hbase + 32 * ks);
      const float4 f1 = *(const float4*)(hbase + 32 * ks + 4);
      float av[8] = {f0.x, f0.y, f0.z, f0.w, f1.x, f1.y, f1.z, f1.w};
      short8 ahi, alo;
#pragma unroll
      for (int j = 0; j < 8; ++j) {
        const short hi = bf16_rne(av[j]);
        ahi[j] = hi;
        alo[j] = bf16_rne(av[j] - bf16_f(hi));
      }
#pragma unroll
      for (int t = 0; t < 4; ++t) {
        const int fb = ((ks * 4 + t) << 9) + lane * 8;
        const short8 bhi = *(const short8*)&Whi[fb];
        const short8 blo = *(const short8*)&Wlo[fb];
        acc[t] = __builtin_amdgcn_mfma_f32_16x16x32_bf16(ahi, bhi, acc[t], 0, 0, 0);
        acc[t] = __builtin_amdgcn_mfma_f32_16x16x32_bf16(ahi, blo, acc[t], 0, 0, 0);
        acc[t] = __builtin_amdgcn_mfma_f32_16x16x32_bf16(alo, bhi, acc[t], 0, 0, 0);
      }
    }

    // store h_lin in bf16: C/D layout col=lane&15, row=q*4+r
#pragma unroll
    for (int t = 0; t < 4; ++t)
#pragma unroll
      for (int r = 0; r < 4; ++r)
        h_lin[(size_t)(row0 + q * 4 + r) * OUT_F + t * 16 + m] =
            (unsigned short)bf16_rne(acc[t][r]);

#pragma unroll
    for (int r = 0; r < 4; ++r) {
      float p = acc[0][r] * a1v[0] + acc[1][r] * a1v[1] +
                acc[2][r] * a1v[2] + acc[3][r] * a1v[3];
      float qq = acc[0][r] * a2v[0] + acc[1][r] * a2v[1] +
                 acc[2][r] * a2v[2] + acc[3][r] * a2v[3];
#pragma unroll
      for (int o = 1; o < 16; o <<= 1) {
        p  += __shfl_xor(p, o, 64);
        qq += __shfl_xor(qq, o, 64);
      }
      if (m == 0) {
        s_src[row0 + q * 4 + r] = p;
        s_dst[row0 + q * 4 + r] = qq;
      }
    }
  }
}

// ---------------------------------------------------------------------------
// Bin body — 512 fine buckets. rowcnt REVERTED (random global atomics cost
// ~50us, measured round 6). Scan over 512 entries = two 256-wide rounds.
// ---------------------------------------------------------------------------
__device__ __forceinline__ void bin_body(
    char* smem, int bbid,
    const int* __restrict__ ei, int* __restrict__ gcur,
    unsigned* __restrict__ regions) {
  unsigned*       reord  = (unsigned*)smem;                  // 8 KB
  unsigned short* bktid  = (unsigned short*)(smem + 8192);   // 4 KB
  int*            hist   = (int*)(smem + 12288);             // 2 KB
  int*            scan_s = (int*)(smem + 14336);             // 2 KB
  int*            adj    = (int*)(smem + 16384);             // 2 KB
  int*            wsum   = (int*)(smem + 18432);             // 16 B

  const int tid = threadIdx.x;
  const int e0  = bbid * TILE;

  hist[tid] = 0;
  hist[256 + tid] = 0;
  __syncthreads();

  int      myb[EPT];
  unsigned myrec[EPT];
#pragma unroll
  for (int k = 0; k < EPT; ++k) {
    const int e = e0 + k * 256 + tid;
    int b = -1; unsigned rec = 0;
    if (e < TOTAL_E) {
      int r, c;
      if (e < E_EDGES) { r = ei[e]; c = ei[E_EDGES + e]; }
      else             { r = e - E_EDGES; c = r; }
      b = (int)((unsigned)r / RPB);
      rec = ((unsigned)(r - b * RPB) << 17) | (unsigned)c;
      atomicAdd(&hist[b], 1);
    }
    myb[k] = b; myrec[k] = rec;
  }
  __syncthreads();

  // issue contended global atomics early; consume results late
  const int v0 = hist[tid];
  const int v1 = hist[256 + tid];
  int base0 = 0, base1 = 0;
  if (v0 > 0) base0 = atomicAdd(&gcur[tid * GC_PAD], v0);
  if (v1 > 0) base1 = atomicAdd(&gcur[(256 + tid) * GC_PAD], v1);

  const int lane = tid & 63, w = tid >> 6;
  // exclusive scan over 512 buckets: two 256-wide rounds
  int incl = v0;
#pragma unroll
  for (int o = 1; o < 64; o <<= 1) {
    const int t = __shfl_up(incl, o, 64);
    if (lane >= o) incl += t;
  }
  if (lane == 63) wsum[w] = incl;
  __syncthreads();
  int wpre = 0;
  for (int i = 0; i < w; ++i) wpre += wsum[i];
  const int T0  = wsum[0] + wsum[1] + wsum[2] + wsum[3];
  const int ex0 = wpre + incl - v0;
  __syncthreads();                      // protect wsum before reuse

  incl = v1;
#pragma unroll
  for (int o = 1; o < 64; o <<= 1) {
    const int t = __shfl_up(incl, o, 64);
    if (lane >= o) incl += t;
  }
  if (lane == 63) wsum[w] = incl;
  __syncthreads();
  wpre = 0;
  for (int i = 0; i < w; ++i) wpre += wsum[i];
  const int ex1 = T0 + wpre + incl - v1;

  scan_s[tid]       = ex0;  adj[tid]       = ex0;
  scan_s[256 + tid] = ex1;  adj[256 + tid] = ex1;
  __syncthreads();

#pragma unroll
  for (int k = 0; k < EPT; ++k) {
    if (myb[k] >= 0) {
      const int pos = atomicAdd(&adj[myb[k]], 1);
      reord[pos]  = myrec[k];
      bktid[pos]  = (unsigned short)myb[k];
    }
  }
  __syncthreads();

  // consume atomic results (vmcnt wait lands here, after the LDS scatter)
  adj[tid]       = base0 - scan_s[tid];
  adj[256 + tid] = base1 - scan_s[256 + tid];
  __syncthreads();

  const int tilesz = scan_s[NB_F - 1] + hist[NB_F - 1];
  for (int i = tid; i < tilesz; i += 256) {
    const int b    = bktid[i];
    const int slot = adj[b] + i;
    if (slot < GCAP) regions[(size_t)b * GCAP + slot] = reord[i];
  }
}

// ---------------------------------------------------------------------------
// Fused front kernel (fusion measured -4us in round 4/5 A/B)
// ---------------------------------------------------------------------------
__global__ __launch_bounds__(256) void k_front(
    const float* __restrict__ h, const float* __restrict__ W,
    const float* __restrict__ a, const int* __restrict__ ei,
    unsigned short* __restrict__ h_lin, float* __restrict__ s_src,
    float* __restrict__ s_dst, int* __restrict__ gcur,
    unsigned* __restrict__ regions) {
  __shared__ alignas(16) char smem[32768];
  const int bid = blockIdx.x;
  if (bid < BIN_BLOCKS) {
    bin_body(smem, bid, ei, gcur, regions);
  } else {
    gemm_body(smem, bid - BIN_BLOCKS, h, W, a, h_lin, s_src, s_dst);
  }
}

// ---------------------------------------------------------------------------
// Kernel C: one block per fine bucket. Phases 1&3 now scan ~3320 records
// (was ~6660 with half the records discarded) and need no range filter.
// ---------------------------------------------------------------------------
__global__ __launch_bounds__(1024) void k_agg(
    const unsigned short* __restrict__ h_lin, const float* __restrict__ s_src,
    const float* __restrict__ s_dst, const int* __restrict__ gcur,
    const unsigned* __restrict__ regions, float* __restrict__ out) {
  __shared__ int   cnt[RPB];
  __shared__ int   off[RPB];
  __shared__ float srcs[RPB];
  __shared__ uint2 pairs[CCAP];      // 36 KB: (col, exp(e)) per record
  __shared__ int   wsum4[4];

  const int b    = blockIdx.x;
  const int tid  = threadIdx.x;
  const int row0 = b * RPB;
  int hr = N_NODES - row0;
  if (hr > RPB) hr = RPB;
  if (hr < 0)   hr = 0;
  const int m = min(gcur[b * GC_PAD], GCAP);
  const unsigned* reg = regions + (size_t)b * GCAP;

  for (int i = tid; i < RPB; i += 1024) {
    cnt[i]  = 0;
    srcs[i] = (i < hr) ? s_src[row0 + i] : 0.f;
  }
  __syncthreads();

  // phase 1: count records per row (all records belong to this block)
  for (int i = tid; i < m; i += 1024) {
    atomicAdd(&cnt[reg[i] >> 17], 1);
  }
  __syncthreads();

  // phase 2: exclusive scan of cnt[0..hr) using first 4 waves
  const int lane = tid & 63, wv = tid >> 6;
  int incl = 0, v = 0;
  if (tid < 256) {
    v = (tid < hr) ? cnt[tid] : 0;
    incl = v;
#pragma unroll
    for (int o = 1; o < 64; o <<= 1) {
      const int t = __shfl_up(incl, o, 64);
      if (lane >= o) incl += t;
    }
    if (lane == 63) wsum4[wv] = incl;
  }
  __syncthreads();
  if (tid < hr) {
    int wpre = 0;
    for (int i = 0; i < wv; ++i) wpre += wsum4[i];
    off[tid] = wpre + incl - v;
  }
  __syncthreads();

  // phase 3: read records (L2-hot), compute ex with full lane utilization,
  // scatter (col, ex) into the LDS CSR — no range filter needed
  for (int i = tid; i < m; i += 1024) {
    const unsigned rec = reg[i];
    const int rl = (int)(rec >> 17);
    const int c  = (int)(rec & 0x1FFFFu);
    float e = srcs[rl] + s_dst[c];
    e = e > 0.f ? e : NEG_SLOPE * e;
    const float ex = __expf(e);
    const int pos = atomicAdd(&off[rl], 1);
    if (pos < CCAP) pairs[pos] = make_uint2((unsigned)c, __float_as_uint(ex));
  }
  __syncthreads();

  // phase 4: per-row weighted sum. One wave per row. Quarter-wave (16 lanes)
  // per edge; each lane owns 4 features. 8 edges per iteration.
  const int qid = lane >> 4;           // quarter id: which edge in group of 4
  const int f4  = (lane & 15) * 4;     // feature base (4 features per lane)
  for (int rl = wv; rl < hr; rl += 16) {
    const int row = row0 + rl;
    const int dcnt  = cnt[rl];
    const int end   = off[rl];
    const int start = end - dcnt;
    const uint2* prow = pairs + start;

    float4v acc = {0.f, 0.f, 0.f, 0.f};
    float dsum = 0.f;
    for (int j = 0; j < dcnt; j += 8) {
      const int ja = j + qid;
      const int jb = j + 4 + qid;
      uint2 pa = make_uint2(0u, 0u), pb = make_uint2(0u, 0u);
      if (ja < dcnt) pa = prow[ja];
      if (jb < dcnt) pb = prow[jb];
      // both gathers issued back-to-back (independent)
      const ushort4 ha = *(const ushort4*)&h_lin[(size_t)pa.x * OUT_F + f4];
      const ushort4 hb = *(const ushort4*)&h_lin[(size_t)pb.x * OUT_F + f4];
      const float ea = __uint_as_float(pa.y);
      const float eb = __uint_as_float(pb.y);
      acc.x = fmaf(ea, bf16u_f(ha.x), acc.x);
      acc.y = fmaf(ea, bf16u_f(ha.y), acc.y);
      acc.z = fmaf(ea, bf16u_f(ha.z), acc.z);
      acc.w = fmaf(ea, bf16u_f(ha.w), acc.w);
      acc.x = fmaf(eb, bf16u_f(hb.x), acc.x);
      acc.y = fmaf(eb, bf16u_f(hb.y), acc.y);
      acc.z = fmaf(eb, bf16u_f(hb.z), acc.z);
      acc.w = fmaf(eb, bf16u_f(hb.w), acc.w);
      dsum += ea + eb;
    }

    // reduce over the 4 quarter-waves (lanes l, l+16, l+32, l+48 share f4)
    acc.x += __shfl_xor(acc.x, 16, 64);
    acc.y += __shfl_xor(acc.y, 16, 64);
    acc.z += __shfl_xor(acc.z, 16, 64);
    acc.w += __shfl_xor(acc.w, 16, 64);
    dsum  += __shfl_xor(dsum, 16, 64);
    acc.x += __shfl_xor(acc.x, 32, 64);
    acc.y += __shfl_xor(acc.y, 32, 64);
    acc.z += __shfl_xor(acc.z, 32, 64);
    acc.w += __shfl_xor(acc.w, 32, 64);
    dsum  += __shfl_xor(dsum, 32, 64);

    if (lane < 16) {
      const float inv = 1.f / dsum;
      float4 o;
      o.x = acc.x * inv; o.y = acc.y * inv;
      o.z = acc.z * inv; o.w = acc.w * inv;
      o.x = o.x > 0.f ? o.x : __expf(o.x) - 1.f;
      o.y = o.y > 0.f ? o.y : __expf(o.y) - 1.f;
      o.z = o.z > 0.f ? o.z : __expf(o.z) - 1.f;
      o.w = o.w > 0.f ? o.w : __expf(o.w) - 1.f;
      *(float4*)&out[(size_t)row * OUT_F + f4] = o;
    }
  }
}

// ---------------------------------------------------------------------------
extern "C" void kernel_launch(void* const* d_in, const int* in_sizes, int n_in,
                              void* d_out, int out_size, void* d_ws, size_t ws_size,
                              hipStream_t stream) {
  const float* h  = (const float*)d_in[0];
  const float* W  = (const float*)d_in[1];
  const float* a  = (const float*)d_in[2];
  const int*   ei = (const int*)d_in[3];
  float* out = (float*)d_out;

  unsigned short* h_lin = (unsigned short*)d_ws;                 // N*64 bf16
  float* s_src = (float*)(h_lin + (size_t)N_NODES * OUT_F);      // N
  float* s_dst = s_src + N_NODES;                                // N
  int*   gcur  = (int*)(s_dst + N_NODES);                        // NB_F*GC_PAD
  unsigned* regions = (unsigned*)(gcur + NB_F * GC_PAD);         // NB_F*GCAP u32

  hipMemsetAsync(gcur, 0, NB_F * GC_PAD * sizeof(int), stream);

  k_front<<<FRONT_BLOCKS, 256, 0, stream>>>(h, W, a, ei, h_lin, s_src, s_dst,
                                            gcur, regions);

  // one block per fine bucket; 512 blocks = 2/CU = full 32 waves/CU
  k_agg<<<NB_F, 1024, 0, stream>>>(h_lin, s_src, s_dst, gcur, regions, out);
}

// Round 8
// 182.434 us; speedup vs baseline: 1.3356x; 1.0701x over previous
//
#include <hip/hip_runtime.h>
#include <cstdint>

#define N_NODES 100000
#define E_EDGES 1600000
#define TOTAL_E (E_EDGES + N_NODES)
#define IN_F 128
#define OUT_F 64
#define NEG_SLOPE 0.2f

#define NB_F 512     // fine buckets: 1 k_agg block per bucket
#define RPB  196     // rows per bucket: ceil(100000/512)
#define GCAP 4608    // per-bucket record capacity (mean 3332, +22 sigma)
#define CCAP 4608    // per-block CSR capacity (== GCAP)
#define TILE 4096    // edges per bin tile (RESTORED: 32B write runs, half the scans)
#define EPT  (TILE / 256)

#define GC_PAD 16    // gcur stride: one counter per 64B cache line

#define BIN_BLOCKS ((TOTAL_E + TILE - 1) / TILE)   // 416
#define GEMM_BLOCKS 608
#define FRONT_BLOCKS (BIN_BLOCKS + GEMM_BLOCKS)    // 1024 = 4 blocks/CU

typedef __attribute__((ext_vector_type(8))) short short8;
typedef __attribute__((ext_vector_type(4))) float float4v;

__device__ __forceinline__ short bf16_rne(float x) {
  unsigned u = __builtin_bit_cast(unsigned, x);
  unsigned r = u + 0x7FFFu + ((u >> 16) & 1u);
  return (short)(r >> 16);
}
__device__ __forceinline__ float bf16_f(short s) {
  unsigned u = ((unsigned)(unsigned short)s) << 16;
  return __builtin_bit_cast(float, u);
}
__device__ __forceinline__ float bf16u_f(unsigned short s) {
  unsigned u = ((unsigned)s) << 16;
  return __builtin_bit_cast(float, u);
}

// ---------------------------------------------------------------------------
// GEMM body (identical math to previous rounds; smem carved from arena)
// ---------------------------------------------------------------------------
__device__ __forceinline__ void gemm_body(
    char* smem, int gbid,
    const float* __restrict__ h, const float* __restrict__ W,
    const float* __restrict__ a, unsigned short* __restrict__ h_lin,
    float* __restrict__ s_src, float* __restrict__ s_dst) {
  short* Whi = (short*)smem;              // 16 KB
  short* Wlo = (short*)(smem + 16384);    // 16 KB

  const int tid = threadIdx.x;
  for (int i = tid; i < OUT_F * IN_F; i += 256) {
    const int n = i >> 7, k = i & 127;
    const float x = W[i];
    const short hi = bf16_rne(x);
    const short lo = bf16_rne(x - bf16_f(hi));
    const int idx = (((k >> 5) * 4 + (n >> 4)) << 9) |
                    (((((k >> 3) & 3) << 4) | (n & 15)) << 3) | (k & 7);
    Whi[idx] = hi;
    Wlo[idx] = lo;
  }
  __syncthreads();

  const int lane = tid & 63;
  const int m    = lane & 15;
  const int q    = lane >> 4;
  const int wgid = gbid * 4 + (tid >> 6);
  const int nw   = GEMM_BLOCKS * 4;

  float a1v[4], a2v[4];
#pragma unroll
  for (int t = 0; t < 4; ++t) {
    a1v[t] = a[t * 16 + m];
    a2v[t] = a[OUT_F + t * 16 + m];
  }

  for (int tile = wgid; tile < N_NODES / 16; tile += nw) {
    const int row0 = tile * 16;
    float4v acc[4] = {{0.f,0.f,0.f,0.f},{0.f,0.f,0.f,0.f},
                      {0.f,0.f,0.f,0.f},{0.f,0.f,0.f,0.f}};

    const float* hbase = h + (size_t)(row0 + m) * IN_F + q * 8;
#pragma unroll
    for (int ks = 0; ks < 4; ++ks) {
      const float4 f0 = *(const float4*)(hbase + 32 * ks);
      const float4 f1 = *(const float4*)(hbase + 32 * ks + 4);
      float av[8] = {f0.x, f0.y, f0.z, f0.w, f1.x, f1.y, f1.z, f1.w};
      short8 ahi, alo;
#pragma unroll
      for (int j = 0; j < 8; ++j) {
        const short hi = bf16_rne(av[j]);
        ahi[j] = hi;
        alo[j] = bf16_rne(av[j] - bf16_f(hi));
      }
#pragma unroll
      for (int t = 0; t < 4; ++t) {
        const int fb = ((ks * 4 + t) << 9) + lane * 8;
        const short8 bhi = *(const short8*)&Whi[fb];
        const short8 blo = *(const short8*)&Wlo[fb];
        acc[t] = __builtin_amdgcn_mfma_f32_16x16x32_bf16(ahi, bhi, acc[t], 0, 0, 0);
        acc[t] = __builtin_amdgcn_mfma_f32_16x16x32_bf16(ahi, blo, acc[t], 0, 0, 0);
        acc[t] = __builtin_amdgcn_mfma_f32_16x16x32_bf16(alo, bhi, acc[t], 0, 0, 0);
      }
    }

    // store h_lin in bf16: C/D layout col=lane&15, row=q*4+r
#pragma unroll
    for (int t = 0; t < 4; ++t)
#pragma unroll
      for (int r = 0; r < 4; ++r)
        h_lin[(size_t)(row0 + q * 4 + r) * OUT_F + t * 16 + m] =
            (unsigned short)bf16_rne(acc[t][r]);

#pragma unroll
    for (int r = 0; r < 4; ++r) {
      float p = acc[0][r] * a1v[0] + acc[1][r] * a1v[1] +
                acc[2][r] * a1v[2] + acc[3][r] * a1v[3];
      float qq = acc[0][r] * a2v[0] + acc[1][r] * a2v[1] +
                 acc[2][r] * a2v[2] + acc[3][r] * a2v[3];
#pragma unroll
      for (int o = 1; o < 16; o <<= 1) {
        p  += __shfl_xor(p, o, 64);
        qq += __shfl_xor(qq, o, 64);
      }
      if (m == 0) {
        s_src[row0 + q * 4 + r] = p;
        s_dst[row0 + q * 4 + r] = qq;
      }
    }
  }
}

// ---------------------------------------------------------------------------
// Bin body — 512 fine buckets, TILE=4096. LDS: reord 16K + bktid 8K +
// hist/scan/adj 6K + wsum = 30.7 KB (fits 32 KB arena).
// ---------------------------------------------------------------------------
__device__ __forceinline__ void bin_body(
    char* smem, int bbid,
    const int* __restrict__ ei, int* __restrict__ gcur,
    unsigned* __restrict__ regions) {
  unsigned*       reord  = (unsigned*)smem;                  // 16 KB
  unsigned short* bktid  = (unsigned short*)(smem + 16384);  // 8 KB
  int*            hist   = (int*)(smem + 24576);             // 2 KB
  int*            scan_s = (int*)(smem + 26624);             // 2 KB
  int*            adj    = (int*)(smem + 28672);             // 2 KB
  int*            wsum   = (int*)(smem + 30720);             // 16 B

  const int tid = threadIdx.x;
  const int e0  = bbid * TILE;

  hist[tid] = 0;
  hist[256 + tid] = 0;
  __syncthreads();

  int      myb[EPT];
  unsigned myrec[EPT];
#pragma unroll
  for (int k = 0; k < EPT; ++k) {
    const int e = e0 + k * 256 + tid;
    int b = -1; unsigned rec = 0;
    if (e < TOTAL_E) {
      int r, c;
      if (e < E_EDGES) { r = ei[e]; c = ei[E_EDGES + e]; }
      else             { r = e - E_EDGES; c = r; }
      b = (int)((unsigned)r / RPB);
      rec = ((unsigned)(r - b * RPB) << 17) | (unsigned)c;
      atomicAdd(&hist[b], 1);
    }
    myb[k] = b; myrec[k] = rec;
  }
  __syncthreads();

  // issue contended global atomics early; consume results late
  const int v0 = hist[tid];
  const int v1 = hist[256 + tid];
  int base0 = 0, base1 = 0;
  if (v0 > 0) base0 = atomicAdd(&gcur[tid * GC_PAD], v0);
  if (v1 > 0) base1 = atomicAdd(&gcur[(256 + tid) * GC_PAD], v1);

  const int lane = tid & 63, w = tid >> 6;
  // exclusive scan over 512 buckets: two 256-wide rounds
  int incl = v0;
#pragma unroll
  for (int o = 1; o < 64; o <<= 1) {
    const int t = __shfl_up(incl, o, 64);
    if (lane >= o) incl += t;
  }
  if (lane == 63) wsum[w] = incl;
  __syncthreads();
  int wpre = 0;
  for (int i = 0; i < w; ++i) wpre += wsum[i];
  const int T0  = wsum[0] + wsum[1] + wsum[2] + wsum[3];
  const int ex0 = wpre + incl - v0;
  __syncthreads();                      // protect wsum before reuse

  incl = v1;
#pragma unroll
  for (int o = 1; o < 64; o <<= 1) {
    const int t = __shfl_up(incl, o, 64);
    if (lane >= o) incl += t;
  }
  if (lane == 63) wsum[w] = incl;
  __syncthreads();
  wpre = 0;
  for (int i = 0; i < w; ++i) wpre += wsum[i];
  const int ex1 = T0 + wpre + incl - v1;

  scan_s[tid]       = ex0;  adj[tid]       = ex0;
  scan_s[256 + tid] = ex1;  adj[256 + tid] = ex1;
  __syncthreads();

#pragma unroll
  for (int k = 0; k < EPT; ++k) {
    if (myb[k] >= 0) {
      const int pos = atomicAdd(&adj[myb[k]], 1);
      reord[pos]  = myrec[k];
      bktid[pos]  = (unsigned short)myb[k];
    }
  }
  __syncthreads();

  // consume atomic results (vmcnt wait lands here, after the LDS scatter)
  adj[tid]       = base0 - scan_s[tid];
  adj[256 + tid] = base1 - scan_s[256 + tid];
  __syncthreads();

  const int tilesz = scan_s[NB_F - 1] + hist[NB_F - 1];
  for (int i = tid; i < tilesz; i += 256) {
    const int b    = bktid[i];
    const int slot = adj[b] + i;
    if (slot < GCAP) regions[(size_t)b * GCAP + slot] = reord[i];
  }
}

// ---------------------------------------------------------------------------
// Fused front kernel
// ---------------------------------------------------------------------------
__global__ __launch_bounds__(256) void k_front(
    const float* __restrict__ h, const float* __restrict__ W,
    const float* __restrict__ a, const int* __restrict__ ei,
    unsigned short* __restrict__ h_lin, float* __restrict__ s_src,
    float* __restrict__ s_dst, int* __restrict__ gcur,
    unsigned* __restrict__ regions) {
  __shared__ alignas(16) char smem[32768];
  const int bid = blockIdx.x;
  if (bid < BIN_BLOCKS) {
    bin_body(smem, bid, ei, gcur, regions);
  } else {
    gemm_body(smem, bid - BIN_BLOCKS, h, W, a, h_lin, s_src, s_dst);
  }
}

// ---------------------------------------------------------------------------
// Kernel C: UNCHANGED (byte-identical to round-7 version).
// ---------------------------------------------------------------------------
__global__ __launch_bounds__(1024) void k_agg(
    const unsigned short* __restrict__ h_lin, const float* __restrict__ s_src,
    const float* __restrict__ s_dst, const int* __restrict__ gcur,
    const unsigned* __restrict__ regions, float* __restrict__ out) {
  __shared__ int   cnt[RPB];
  __shared__ int   off[RPB];
  __shared__ float srcs[RPB];
  __shared__ uint2 pairs[CCAP];      // 36 KB: (col, exp(e)) per record
  __shared__ int   wsum4[4];

  const int b    = blockIdx.x;
  const int tid  = threadIdx.x;
  const int row0 = b * RPB;
  int hr = N_NODES - row0;
  if (hr > RPB) hr = RPB;
  if (hr < 0)   hr = 0;
  const int m = min(gcur[b * GC_PAD], GCAP);
  const unsigned* reg = regions + (size_t)b * GCAP;

  for (int i = tid; i < RPB; i += 1024) {
    cnt[i]  = 0;
    srcs[i] = (i < hr) ? s_src[row0 + i] : 0.f;
  }
  __syncthreads();

  // phase 1: count records per row (all records belong to this block)
  for (int i = tid; i < m; i += 1024) {
    atomicAdd(&cnt[reg[i] >> 17], 1);
  }
  __syncthreads();

  // phase 2: exclusive scan of cnt[0..hr) using first 4 waves
  const int lane = tid & 63, wv = tid >> 6;
  int incl = 0, v = 0;
  if (tid < 256) {
    v = (tid < hr) ? cnt[tid] : 0;
    incl = v;
#pragma unroll
    for (int o = 1; o < 64; o <<= 1) {
      const int t = __shfl_up(incl, o, 64);
      if (lane >= o) incl += t;
    }
    if (lane == 63) wsum4[wv] = incl;
  }
  __syncthreads();
  if (tid < hr) {
    int wpre = 0;
    for (int i = 0; i < wv; ++i) wpre += wsum4[i];
    off[tid] = wpre + incl - v;
  }
  __syncthreads();

  // phase 3: read records (L2-hot), compute ex with full lane utilization,
  // scatter (col, ex) into the LDS CSR — no range filter needed
  for (int i = tid; i < m; i += 1024) {
    const unsigned rec = reg[i];
    const int rl = (int)(rec >> 17);
    const int c  = (int)(rec & 0x1FFFFu);
    float e = srcs[rl] + s_dst[c];
    e = e > 0.f ? e : NEG_SLOPE * e;
    const float ex = __expf(e);
    const int pos = atomicAdd(&off[rl], 1);
    if (pos < CCAP) pairs[pos] = make_uint2((unsigned)c, __float_as_uint(ex));
  }
  __syncthreads();

  // phase 4: per-row weighted sum. One wave per row. Quarter-wave (16 lanes)
  // per edge; each lane owns 4 features. 8 edges per iteration.
  const int qid = lane >> 4;           // quarter id: which edge in group of 4
  const int f4  = (lane & 15) * 4;     // feature base (4 features per lane)
  for (int rl = wv; rl < hr; rl += 16) {
    const int row = row0 + rl;
    const int dcnt  = cnt[rl];
    const int end   = off[rl];
    const int start = end - dcnt;
    const uint2* prow = pairs + start;

    float4v acc = {0.f, 0.f, 0.f, 0.f};
    float dsum = 0.f;
    for (int j = 0; j < dcnt; j += 8) {
      const int ja = j + qid;
      const int jb = j + 4 + qid;
      uint2 pa = make_uint2(0u, 0u), pb = make_uint2(0u, 0u);
      if (ja < dcnt) pa = prow[ja];
      if (jb < dcnt) pb = prow[jb];
      // both gathers issued back-to-back (independent)
      const ushort4 ha = *(const ushort4*)&h_lin[(size_t)pa.x * OUT_F + f4];
      const ushort4 hb = *(const ushort4*)&h_lin[(size_t)pb.x * OUT_F + f4];
      const float ea = __uint_as_float(pa.y);
      const float eb = __uint_as_float(pb.y);
      acc.x = fmaf(ea, bf16u_f(ha.x), acc.x);
      acc.y = fmaf(ea, bf16u_f(ha.y), acc.y);
      acc.z = fmaf(ea, bf16u_f(ha.z), acc.z);
      acc.w = fmaf(ea, bf16u_f(ha.w), acc.w);
      acc.x = fmaf(eb, bf16u_f(hb.x), acc.x);
      acc.y = fmaf(eb, bf16u_f(hb.y), acc.y);
      acc.z = fmaf(eb, bf16u_f(hb.z), acc.z);
      acc.w = fmaf(eb, bf16u_f(hb.w), acc.w);
      dsum += ea + eb;
    }

    // reduce over the 4 quarter-waves (lanes l, l+16, l+32, l+48 share f4)
    acc.x += __shfl_xor(acc.x, 16, 64);
    acc.y += __shfl_xor(acc.y, 16, 64);
    acc.z += __shfl_xor(acc.z, 16, 64);
    acc.w += __shfl_xor(acc.w, 16, 64);
    dsum  += __shfl_xor(dsum, 16, 64);
    acc.x += __shfl_xor(acc.x, 32, 64);
    acc.y += __shfl_xor(acc.y, 32, 64);
    acc.z += __shfl_xor(acc.z, 32, 64);
    acc.w += __shfl_xor(acc.w, 32, 64);
    dsum  += __shfl_xor(dsum, 32, 64);

    if (lane < 16) {
      const float inv = 1.f / dsum;
      float4 o;
      o.x = acc.x * inv; o.y = acc.y * inv;
      o.z = acc.z * inv; o.w = acc.w * inv;
      o.x = o.x > 0.f ? o.x : __expf(o.x) - 1.f;
      o.y = o.y > 0.f ? o.y : __expf(o.y) - 1.f;
      o.z = o.z > 0.f ? o.z : __expf(o.z) - 1.f;
      o.w = o.w > 0.f ? o.w : __expf(o.w) - 1.f;
      *(float4*)&out[(size_t)row * OUT_F + f4] = o;
    }
  }
}

// ---------------------------------------------------------------------------
extern "C" void kernel_launch(void* const* d_in, const int* in_sizes, int n_in,
                              void* d_out, int out_size, void* d_ws, size_t ws_size,
                              hipStream_t stream) {
  const float* h  = (const float*)d_in[0];
  const float* W  = (const float*)d_in[1];
  const float* a  = (const float*)d_in[2];
  const int*   ei = (const int*)d_in[3];
  float* out = (float*)d_out;

  unsigned short* h_lin = (unsigned short*)d_ws;                 // N*64 bf16
  float* s_src = (float*)(h_lin + (size_t)N_NODES * OUT_F);      // N
  float* s_dst = s_src + N_NODES;                                // N
  int*   gcur  = (int*)(s_dst + N_NODES);                        // NB_F*GC_PAD
  unsigned* regions = (unsigned*)(gcur + NB_F * GC_PAD);         // NB_F*GCAP u32

  hipMemsetAsync(gcur, 0, NB_F * GC_PAD * sizeof(int), stream);

  k_front<<<FRONT_BLOCKS, 256, 0, stream>>>(h, W, a, ei, h_lin, s_src, s_dst,
                                            gcur, regions);

  // one block per fine bucket; 512 blocks = 2/CU = full 32 waves/CU
  k_agg<<<NB_F, 1024, 0, stream>>>(h_lin, s_src, s_dst, gcur, regions, out);
}

// Round 10
// 171.587 us; speedup vs baseline: 1.4201x; 1.0632x over previous
//
#include <hip/hip_runtime.h>
#include <cstdint>

#define N_NODES 100000
#define E_EDGES 1600000
#define TOTAL_E (E_EDGES + N_NODES)
#define IN_F 128
#define OUT_F 64
#define NEG_SLOPE 0.2f

#define NB   256     // coarse buckets (round-4/7 proven)
#define RPB  391     // rows per bucket: ceil(100000/256)
#define GCAP 8192    // per-bucket record capacity
#define TILE 4096    // edges per k_bin tile
#define EPT  (TILE / 256)
#define HALF_R 196   // rows in half 0 (half 1 gets RPB-196 = 195)
#define CCAP 4608    // per-half CSR capacity (mean 3332, +22 sigma)

#define GC_PAD 16    // gcur stride: one counter per 64B cache line

#define BIN_BLOCKS ((TOTAL_E + TILE - 1) / TILE)   // 416
#define GEMM_BLOCKS 608                            // grid-stride absorbs
#define FRONT_BLOCKS (BIN_BLOCKS + GEMM_BLOCKS)    // 1024 = 4 blocks/CU

typedef __attribute__((ext_vector_type(8))) short short8;
typedef __attribute__((ext_vector_type(4))) float float4v;

__device__ __forceinline__ short bf16_rne(float x) {
  unsigned u = __builtin_bit_cast(unsigned, x);
  unsigned r = u + 0x7FFFu + ((u >> 16) & 1u);
  return (short)(r >> 16);
}
__device__ __forceinline__ float bf16_f(short s) {
  unsigned u = ((unsigned)(unsigned short)s) << 16;
  return __builtin_bit_cast(float, u);
}
__device__ __forceinline__ float bf16u_f(unsigned short s) {
  unsigned u = ((unsigned)s) << 16;
  return __builtin_bit_cast(float, u);
}

// ---------------------------------------------------------------------------
// GEMM body (identical math to previous rounds; smem carved from arena)
// ---------------------------------------------------------------------------
__device__ __forceinline__ void gemm_body(
    char* smem, int gbid,
    const float* __restrict__ h, const float* __restrict__ W,
    const float* __restrict__ a, unsigned short* __restrict__ h_lin,
    float* __restrict__ s_src, float* __restrict__ s_dst) {
  short* Whi = (short*)smem;              // 16 KB
  short* Wlo = (short*)(smem + 16384);    // 16 KB

  const int tid = threadIdx.x;
  for (int i = tid; i < OUT_F * IN_F; i += 256) {
    const int n = i >> 7, k = i & 127;
    const float x = W[i];
    const short hi = bf16_rne(x);
    const short lo = bf16_rne(x - bf16_f(hi));
    const int idx = (((k >> 5) * 4 + (n >> 4)) << 9) |
                    (((((k >> 3) & 3) << 4) | (n & 15)) << 3) | (k & 7);
    Whi[idx] = hi;
    Wlo[idx] = lo;
  }
  __syncthreads();

  const int lane = tid & 63;
  const int m    = lane & 15;
  const int q    = lane >> 4;
  const int wgid = gbid * 4 + (tid >> 6);
  const int nw   = GEMM_BLOCKS * 4;

  float a1v[4], a2v[4];
#pragma unroll
  for (int t = 0; t < 4; ++t) {
    a1v[t] = a[t * 16 + m];
    a2v[t] = a[OUT_F + t * 16 + m];
  }

  for (int tile = wgid; tile < N_NODES / 16; tile += nw) {
    const int row0 = tile * 16;
    float4v acc[4] = {{0.f,0.f,0.f,0.f},{0.f,0.f,0.f,0.f},
                      {0.f,0.f,0.f,0.f},{0.f,0.f,0.f,0.f}};

    const float* hbase = h + (size_t)(row0 + m) * IN_F + q * 8;
#pragma unroll
    for (int ks = 0; ks < 4; ++ks) {
      const float4 f0 = *(const float4*)(hbase + 32 * ks);
      const float4 f1 = *(const float4*)(hbase + 32 * ks + 4);
      float av[8] = {f0.x, f0.y, f0.z, f0.w, f1.x, f1.y, f1.z, f1.w};
      short8 ahi, alo;
#pragma unroll
      for (int j = 0; j < 8; ++j) {
        const short hi = bf16_rne(av[j]);
        ahi[j] = hi;
        alo[j] = bf16_rne(av[j] - bf16_f(hi));
      }
#pragma unroll
      for (int t = 0; t < 4; ++t) {
        const int fb = ((ks * 4 + t) << 9) + lane * 8;
        const short8 bhi = *(const short8*)&Whi[fb];
        const short8 blo = *(const short8*)&Wlo[fb];
        acc[t] = __builtin_amdgcn_mfma_f32_16x16x32_bf16(ahi, bhi, acc[t], 0, 0, 0);
        acc[t] = __builtin_amdgcn_mfma_f32_16x16x32_bf16(ahi, blo, acc[t], 0, 0, 0);
        acc[t] = __builtin_amdgcn_mfma_f32_16x16x32_bf16(alo, bhi, acc[t], 0, 0, 0);
      }
    }

    // store h_lin in bf16: C/D layout col=lane&15, row=q*4+r
#pragma unroll
    for (int t = 0; t < 4; ++t)
#pragma unroll
      for (int r = 0; r < 4; ++r)
        h_lin[(size_t)(row0 + q * 4 + r) * OUT_F + t * 16 + m] =
            (unsigned short)bf16_rne(acc[t][r]);

#pragma unroll
    for (int r = 0; r < 4; ++r) {
      float p = acc[0][r] * a1v[0] + acc[1][r] * a1v[1] +
                acc[2][r] * a1v[2] + acc[3][r] * a1v[3];
      float qq = acc[0][r] * a2v[0] + acc[1][r] * a2v[1] +
                 acc[2][r] * a2v[2] + acc[3][r] * a2v[3];
#pragma unroll
      for (int o = 1; o < 16; o <<= 1) {
        p  += __shfl_xor(p, o, 64);
        qq += __shfl_xor(qq, o, 64);
      }
      if (m == 0) {
        s_src[row0 + q * 4 + r] = p;
        s_dst[row0 + q * 4 + r] = qq;
      }
    }
  }
}

// ---------------------------------------------------------------------------
// Bin body — gcur atomic padded to one counter per 64B line, issued right
// after the hist barrier with its result consumed after the LDS scatter.
// ---------------------------------------------------------------------------
__device__ __forceinline__ void bin_body(
    char* smem, int bbid,
    const int* __restrict__ ei, int* __restrict__ gcur,
    unsigned* __restrict__ regions) {
  unsigned*      reord  = (unsigned*)smem;                // 16 KB
  unsigned char* bktid  = (unsigned char*)(smem + 16384); // 4 KB
  int*           hist   = (int*)(smem + 20480);           // 1 KB
  int*           scan_s = (int*)(smem + 21504);           // 1 KB
  int*           adj    = (int*)(smem + 22528);           // 1 KB
  int*           wsum   = (int*)(smem + 23552);           // 16 B

  const int tid = threadIdx.x;
  const int e0  = bbid * TILE;

  hist[tid] = 0;
  __syncthreads();

  int      myb[EPT];
  unsigned myrec[EPT];
#pragma unroll
  for (int k = 0; k < EPT; ++k) {
    const int e = e0 + k * 256 + tid;
    int b = -1; unsigned rec = 0;
    if (e < TOTAL_E) {
      int r, c;
      if (e < E_EDGES) { r = ei[e]; c = ei[E_EDGES + e]; }
      else             { r = e - E_EDGES; c = r; }
      b = (int)((unsigned)r / RPB);
      rec = ((unsigned)(r - b * RPB) << 17) | (unsigned)c;
      atomicAdd(&hist[b], 1);
    }
    myb[k] = b; myrec[k] = rec;
  }
  __syncthreads();

  // ---- issue the contended global atomic EARLY; consume its result late ----
  const int v = hist[tid];
  int base = 0;
  if (v > 0) base = atomicAdd(&gcur[tid * GC_PAD], v);

  const int lane = tid & 63, w = tid >> 6;
  {
    int incl = v;
#pragma unroll
    for (int o = 1; o < 64; o <<= 1) {
      const int t = __shfl_up(incl, o, 64);
      if (lane >= o) incl += t;
    }
    if (lane == 63) wsum[w] = incl;
    __syncthreads();
    int wpre = 0;
    for (int i = 0; i < w; ++i) wpre += wsum[i];
    scan_s[tid] = wpre + incl - v;
    adj[tid]    = wpre + incl - v;
  }
  __syncthreads();

#pragma unroll
  for (int k = 0; k < EPT; ++k) {
    if (myb[k] >= 0) {
      const int pos = atomicAdd(&adj[myb[k]], 1);
      reord[pos]  = myrec[k];
      bktid[pos]  = (unsigned char)myb[k];
    }
  }
  __syncthreads();

  // consume the atomic result (s_waitcnt lands here, after the LDS scatter)
  adj[tid] = base - scan_s[tid];
  __syncthreads();

  const int tilesz = scan_s[NB - 1] + hist[NB - 1];
  for (int i = tid; i < tilesz; i += 256) {
    const int b    = bktid[i];
    const int slot = adj[b] + i;
    if (slot < GCAP) regions[(size_t)b * GCAP + slot] = reord[i];
  }
}

// ---------------------------------------------------------------------------
// Fused front kernel — type assigned by 256-block CHUNK so the co-resident
// set {b, b+256, b+512, b+768} on each CU mixes bin and gemm blocks.
// ---------------------------------------------------------------------------
__global__ __launch_bounds__(256) void k_front(
    const float* __restrict__ h, const float* __restrict__ W,
    const float* __restrict__ a, const int* __restrict__ ei,
    unsigned short* __restrict__ h_lin, float* __restrict__ s_src,
    float* __restrict__ s_dst, int* __restrict__ gcur,
    unsigned* __restrict__ regions) {
  __shared__ alignas(16) char smem[32768];
  const int bid   = blockIdx.x;
  const int chunk = bid >> 8;
  const int pos   = bid & 255;
  if (chunk == 0) {
    bin_body(smem, pos, ei, gcur, regions);
  } else if (chunk == 1) {
    if (pos < 160) bin_body(smem, 256 + pos, ei, gcur, regions);
    else           gemm_body(smem, pos - 160, h, W, a, h_lin, s_src, s_dst);
  } else if (chunk == 2) {
    gemm_body(smem, 96 + pos, h, W, a, h_lin, s_src, s_dst);
  } else {
    gemm_body(smem, 352 + pos, h, W, a, h_lin, s_src, s_dst);
  }
}

// ---------------------------------------------------------------------------
// Kernel C: quarter-wave phase 4, gcur read with padded stride.
// ---------------------------------------------------------------------------
__global__ __launch_bounds__(1024) void k_agg(
    const unsigned short* __restrict__ h_lin, const float* __restrict__ s_src,
    const float* __restrict__ s_dst, const int* __restrict__ gcur,
    const unsigned* __restrict__ regions, float* __restrict__ out) {
  __shared__ int   cnt[HALF_R];
  __shared__ int   off[HALF_R];
  __shared__ float srcs[HALF_R];
  __shared__ uint2 pairs[CCAP];      // 36 KB: (col, exp(e)) per record
  __shared__ int   wsum4[4];

  const int blk  = blockIdx.x;
  const int b    = blk >> 1;
  const int half = blk & 1;
  const int rlo  = half * HALF_R;
  const int hr   = half ? (RPB - HALF_R) : HALF_R;   // 195 : 196
  const int tid  = threadIdx.x;
  const int row0 = b * RPB + rlo;
  const int m    = min(gcur[b * GC_PAD], GCAP);
  const unsigned* reg = regions + (size_t)b * GCAP;

  for (int i = tid; i < HALF_R; i += 1024) {
    cnt[i]  = 0;
    srcs[i] = (i < hr && row0 + i < N_NODES) ? s_src[row0 + i] : 0.f;
  }
  __syncthreads();

  // phase 1: count records per row (coalesced read; no per-thread buffering)
  for (int i = tid; i < m; i += 1024) {
    const int rl = (int)(reg[i] >> 17) - rlo;
    if (rl >= 0 && rl < hr) atomicAdd(&cnt[rl], 1);
  }
  __syncthreads();

  // phase 2: exclusive scan of cnt[0..hr) using first 4 waves
  const int lane = tid & 63, wv = tid >> 6;
  int incl = 0, v = 0;
  if (tid < 256) {
    v = (tid < hr) ? cnt[tid] : 0;
    incl = v;
#pragma unroll
    for (int o = 1; o < 64; o <<= 1) {
      const int t = __shfl_up(incl, o, 64);
      if (lane >= o) incl += t;
    }
    if (lane == 63) wsum4[wv] = incl;
  }
  __syncthreads();
  if (tid < hr) {
    int wpre = 0;
    for (int i = 0; i < wv; ++i) wpre += wsum4[i];
    off[tid] = wpre + incl - v;
  }
  __syncthreads();

  // phase 3: re-read records (L2-hot), compute ex inline with full lane
  // utilization, scatter (col, ex) into the LDS CSR
  for (int i = tid; i < m; i += 1024) {
    const unsigned rec = reg[i];
    const int rl = (int)(rec >> 17) - rlo;
    if (rl >= 0 && rl < hr) {
      const int c = (int)(rec & 0x1FFFFu);
      float e = srcs[rl] + s_dst[c];
      e = e > 0.f ? e : NEG_SLOPE * e;
      const float ex = __expf(e);
      const int pos = atomicAdd(&off[rl], 1);
      if (pos < CCAP) pairs[pos] = make_uint2((unsigned)c, __float_as_uint(ex));
    }
  }
  __syncthreads();

  // phase 4: per-row weighted sum. One wave per row. Quarter-wave (16 lanes)
  // per edge; each lane owns 4 features. 8 edges per iteration, both load
  // groups issued before any use (2-deep MLP).
  const int qid = lane >> 4;           // quarter id: which edge in group of 4
  const int f4  = (lane & 15) * 4;     // feature base (4 features per lane)
  for (int rl = wv; rl < hr; rl += 16) {
    const int row = row0 + rl;
    if (row >= N_NODES) break;
    const int dcnt  = cnt[rl];
    const int end   = off[rl];
    const int start = end - dcnt;
    const uint2* prow = pairs + start;

    float4v acc = {0.f, 0.f, 0.f, 0.f};
    float dsum = 0.f;
    for (int j = 0; j < dcnt; j += 8) {
      const int ja = j + qid;
      const int jb = j + 4 + qid;
      uint2 pa = make_uint2(0u, 0u), pb = make_uint2(0u, 0u);
      if (ja < dcnt) pa = prow[ja];
      if (jb < dcnt) pb = prow[jb];
      // both gathers issued back-to-back (independent)
      const ushort4 ha = *(const ushort4*)&h_lin[(size_t)pa.x * OUT_F + f4];
      const ushort4 hb = *(const ushort4*)&h_lin[(size_t)pb.x * OUT_F + f4];
      const float ea = __uint_as_float(pa.y);
      const float eb = __uint_as_float(pb.y);
      acc.x = fmaf(ea, bf16u_f(ha.x), acc.x);
      acc.y = fmaf(ea, bf16u_f(ha.y), acc.y);
      acc.z = fmaf(ea, bf16u_f(ha.z), acc.z);
      acc.w = fmaf(ea, bf16u_f(ha.w), acc.w);
      acc.x = fmaf(eb, bf16u_f(hb.x), acc.x);
      acc.y = fmaf(eb, bf16u_f(hb.y), acc.y);
      acc.z = fmaf(eb, bf16u_f(hb.z), acc.z);
      acc.w = fmaf(eb, bf16u_f(hb.w), acc.w);
      dsum += ea + eb;
    }

    // reduce over the 4 quarter-waves (lanes l, l+16, l+32, l+48 share f4)
    acc.x += __shfl_xor(acc.x, 16, 64);
    acc.y += __shfl_xor(acc.y, 16, 64);
    acc.z += __shfl_xor(acc.z, 16, 64);
    acc.w += __shfl_xor(acc.w, 16, 64);
    dsum  += __shfl_xor(dsum, 16, 64);
    acc.x += __shfl_xor(acc.x, 32, 64);
    acc.y += __shfl_xor(acc.y, 32, 64);
    acc.z += __shfl_xor(acc.z, 32, 64);
    acc.w += __shfl_xor(acc.w, 32, 64);
    dsum  += __shfl_xor(dsum, 32, 64);

    if (lane < 16) {
      const float inv = 1.f / dsum;
      float4 o;
      o.x = acc.x * inv; o.y = acc.y * inv;
      o.z = acc.z * inv; o.w = acc.w * inv;
      o.x = o.x > 0.f ? o.x : __expf(o.x) - 1.f;
      o.y = o.y > 0.f ? o.y : __expf(o.y) - 1.f;
      o.z = o.z > 0.f ? o.z : __expf(o.z) - 1.f;
      o.w = o.w > 0.f ? o.w : __expf(o.w) - 1.f;
      *(float4*)&out[(size_t)row * OUT_F + f4] = o;
    }
  }
}

// ---------------------------------------------------------------------------
extern "C" void kernel_launch(void* const* d_in, const int* in_sizes, int n_in,
                              void* d_out, int out_size, void* d_ws, size_t ws_size,
                              hipStream_t stream) {
  const float* h  = (const float*)d_in[0];
  const float* W  = (const float*)d_in[1];
  const float* a  = (const float*)d_in[2];
  const int*   ei = (const int*)d_in[3];
  float* out = (float*)d_out;

  unsigned short* h_lin = (unsigned short*)d_ws;                 // N*64 bf16
  float* s_src = (float*)(h_lin + (size_t)N_NODES * OUT_F);      // N
  float* s_dst = s_src + N_NODES;                                // N
  int*   gcur  = (int*)(s_dst + N_NODES);                        // NB*GC_PAD
  unsigned* regions = (unsigned*)(gcur + NB * GC_PAD);           // NB*GCAP u32

  hipMemsetAsync(gcur, 0, NB * GC_PAD * sizeof(int), stream);

  k_front<<<FRONT_BLOCKS, 256, 0, stream>>>(h, W, a, ei, h_lin, s_src, s_dst,
                                            gcur, regions);

  // 2 blocks per bucket -> 512 blocks = 2/CU = full 32 waves/CU
  k_agg<<<NB * 2, 1024, 0, stream>>>(h_lin, s_src, s_dst, gcur, regions, out);
}